// Round 8
// baseline (62.567 us; speedup 1.0000x reference)
//
#include <hip/hip_runtime.h>

// YOLO-style loss, B=131072, GRID=7, CELLS=49, 11 floats/cell.
// R2: non-atomic partial reduction (77us). R3: occupancy CPC=512 (58.2us).
// R4: persistent pipeline regressed (62.7) - reverted.
// R5: algebraic split bulk(0.5*pc^2)+heavy(one-cells), scattered dwords
//     (59.5) -> proved compute is NOT the wall.
// R6: minimal dense float4 read structure -> CRASHED on my unroll-4 tail
//     guard (r+1/r+2 lanes unguarded at r=32 -> OOB read).
// R7: R6 with the guard fixed: 32 rounds unroll-4 (exact), round 32 + tail
//     separate. Discriminates read-BW roofline (~59us) vs structural (~45-52).

constexpr int BLOCK = 256;
constexpr int B_SAMPLES = 131072;
constexpr int TOTAL_CELLS = B_SAMPLES * 49;       // 6422528
constexpr unsigned NF4 = 17661952u;               // total float4 in outputs
constexpr int BULK_BLOCKS = 2048;                 // 8 blocks/CU
constexpr int HEAVY_BLOCKS = B_SAMPLES / BLOCK;   // 512
constexpr int GRID_TOTAL = BULK_BLOCKS + HEAVY_BLOCKS;
constexpr unsigned BT = BULK_BLOCKS * BLOCK;      // 524288 bulk threads
constexpr int FULLR = NF4 / BT;                   // 33 full rounds
constexpr int FULLR4 = (FULLR / 4) * 4;           // 32 (unroll-4 exact part)

__device__ __forceinline__ double block_reduce_f64(double a, double* wred, int t)
{
#pragma unroll
    for (int off = 32; off > 0; off >>= 1)
        a += __shfl_down(a, off);
    if ((t & 63) == 0) wred[t >> 6] = a;
    __syncthreads();
    double s = 0.0;
    if (t == 0) {
#pragma unroll
        for (int i = 0; i < BLOCK / 64; ++i) s += wred[i];
    }
    return s;
}

__device__ __forceinline__ float bulk_f4(const float4* __restrict__ o4,
                                         const float* __restrict__ target,
                                         unsigned f)
{
    const float4 v = o4[f];
    const unsigned m = (4u * (f % 11u)) % 11u;     // (4f) mod 11
    const bool isp0 = (m - 1u) < 4u;               // m in {1,2,3,4}
    const bool isp1 = (m - 6u) < 4u;               // m in {6,7,8,9}
    const unsigned jj = isp0 ? (4u - m) : (9u - m);
    float val = v.x;
    val = (jj == 1u) ? v.y : val;
    val = (jj == 2u) ? v.z : val;
    val = (jj == 3u) ? v.w : val;
    bool take = isp0;
    if (isp1) {                                    // predicated L2-hit load
        const unsigned d = 4u * f + jj;            // global dword index
        const unsigned b = d / 539u;               // sample
        take = (target[8u * (size_t)b + 4u] != -1.0f);
    }
    const float u = take ? val : 0.0f;
    return u * u;
}

// ---- heavy-role helpers (bit-exact IEEE path, unchanged from R5) ----
__device__ __forceinline__ int cands(float tx, int* out)
{
    int ig = (int)(tx * 7.0f);
    if (ig < 0) ig = 0;
    if (ig > 6) ig = 6;
    int lo = ig - 1; if (lo < 0) lo = 0;
    int hi = ig + 1; if (hi > 6) hi = 6;
    int n = 0;
    for (int i = lo; i <= hi; ++i) {
        const float xl = (float)i / 7.0f;
        const float xh = xl + (1.0f / 7.0f);
        if (xl <= tx && tx <= xh) out[n++] = i;
    }
    return n;
}

__device__ __forceinline__ float iou_f(float px, float py, float pw, float ph,
                                       float tx, float ty, float tw, float th)
{
#pragma clang fp contract(off)
    const float ix = fabsf(fmaxf(px - 0.5f * pw, tx - 0.5f * tw)
                         - fminf(px + 0.5f * pw, tx + 0.5f * tw));
    const float iy = fabsf(fmaxf(py - 0.5f * ph, ty - 0.5f * th)
                         - fminf(py + 0.5f * ph, ty + 0.5f * th));
    const float inter = ix * iy;
    const float uni = pw * ph + tw * th - inter;
    return inter / uni;
}

__device__ __forceinline__ double proc_cell(const float* __restrict__ outputs,
                                            unsigned g, float4 T0, float4 T1,
                                            bool v1, bool o0, bool o1)
{
#pragma clang fp contract(off)
    const float* cp = outputs + 11u * (size_t)g;
    const float f0 = cp[0], f1 = cp[1], f2 = cp[2], f3 = cp[3], f4 = cp[4];
    const float f5 = cp[5], f6 = cp[6], f7 = cp[7], f8 = cp[8], f9 = cp[9];
    const float f10 = cp[10];

    const float conf0 = iou_f(f0, f1, f2, f3, T0.x, T0.y, T0.z, T0.w);
    const float conf1 = iou_f(f5, f6, f7, f8, T1.x, T1.y, T1.z, T1.w);

    double corr = 0.0;
    if (o0) {
        const float d0 = T0.x - f0, d1 = T0.y - f1;
        const float d2 = sqrtf(T0.z) - sqrtf(f2);
        const float d3 = sqrtf(T0.w) - sqrtf(f3);
        const float coord = ((d0 * d0 + d1 * d1) + d2 * d2) + d3 * d3;
        const float dc = conf0 - f4;
        corr += (double)(5.0f * coord + dc * dc) - (double)(0.5f * (f4 * f4));
    }
    if (o1) {
        const float d0 = T1.x - f5, d1 = T1.y - f6;
        const float d2 = sqrtf(T1.z) - sqrtf(f7);
        const float d3 = sqrtf(T1.w) - sqrtf(f8);
        const float coord = ((d0 * d0 + d1 * d1) + d2 * d2) + d3 * d3;
        const float dc = conf1 - f9;
        corr += (double)(5.0f * coord + dc * dc) - (double)(0.5f * (f9 * f9));
    }
    const float sum_conf = conf0 + (v1 ? conf1 : 0.0f);
    const float dcls = f10 - sum_conf;
    corr += (double)(dcls * dcls);
    return corr;
}

__global__ __launch_bounds__(BLOCK) void yolo_loss_kernel(
    const float* __restrict__ outputs,
    const float* __restrict__ target,
    double* __restrict__ part)
{
    __shared__ double wred[BLOCK / 64];
    const int t = threadIdx.x;
    const unsigned blk = blockIdx.x;
    double a = 0.0;

    if (blk < BULK_BLOCKS) {
        // ---- bulk: dense float4 stream, register-only pc^2 accumulation
        const float4* o4 = reinterpret_cast<const float4*>(outputs);
        const unsigned tid = blk * BLOCK + t;
        float s0 = 0.0f, s1 = 0.0f, s2 = 0.0f, s3 = 0.0f;
#pragma unroll 4
        for (int r = 0; r < FULLR4; r += 4) {      // 32 rounds, 4-deep MLP
            s0 += bulk_f4(o4, target, tid + (unsigned)(r + 0) * BT);
            s1 += bulk_f4(o4, target, tid + (unsigned)(r + 1) * BT);
            s2 += bulk_f4(o4, target, tid + (unsigned)(r + 2) * BT);
            s3 += bulk_f4(o4, target, tid + (unsigned)(r + 3) * BT);
        }
        // round 32 (full) ...
        s0 += bulk_f4(o4, target, tid + (unsigned)FULLR4 * BT);
        // ... and partial tail round 33
        {
            const unsigned f = tid + (unsigned)FULLR * BT;
            if (f < NF4) s1 += bulk_f4(o4, target, f);
        }
        a = 0.5 * (double)(((s0 + s1) + s2) + s3);
    } else {
        // ---- heavy: one thread per sample; exact one-cell corrections
        const unsigned b = (blk - BULK_BLOCKS) * BLOCK + t;
        const float4* tg4 = reinterpret_cast<const float4*>(target);
        const float4 T0 = tg4[2u * b];
        const float4 T1 = tg4[2u * b + 1u];
        const bool v1 = (T1.x != -1.0f);

        int cx0[3], cy0[3], cx1[3], cy1[3];
        int nx0 = cands(T0.x, cx0);
        int ny0 = cands(T0.y, cy0);
        int nx1 = 0, ny1 = 0;
        if (v1) { nx1 = cands(T1.x, cx1); ny1 = cands(T1.y, cy1); }

        const unsigned base = 49u * b;
        for (int ai = 0; ai < nx0; ++ai)
            for (int bi = 0; bi < ny0; ++bi) {
                const int s = cy0[bi] * 7 + cx0[ai];
                bool o1 = false;
                for (int ci = 0; ci < nx1; ++ci)
                    for (int di = 0; di < ny1; ++di)
                        if (cy1[di] * 7 + cx1[ci] == s) o1 = true;
                a += proc_cell(outputs, base + s, T0, T1, v1, true, o1);
            }
        for (int ci = 0; ci < nx1; ++ci)
            for (int di = 0; di < ny1; ++di) {
                const int s = cy1[di] * 7 + cx1[ci];
                bool o0 = false;
                for (int ai = 0; ai < nx0; ++ai)
                    for (int bi = 0; bi < ny0; ++bi)
                        if (cy0[bi] * 7 + cx0[ai] == s) o0 = true;
                if (!o0)
                    a += proc_cell(outputs, base + s, T0, T1, v1, false, true);
            }
    }

    const double s = block_reduce_f64(a, wred, t);
    if (t == 0) part[blk] = s;
}

constexpr int RBLOCK = 1024;
__global__ __launch_bounds__(RBLOCK) void reduce_kernel(
    const double* __restrict__ part, float* __restrict__ out)
{
    __shared__ double wred[RBLOCK / 64];
    const int t = threadIdx.x;
    double a = 0.0;
    for (int i = t; i < GRID_TOTAL; i += RBLOCK)
        a += part[i];
#pragma unroll
    for (int off = 32; off > 0; off >>= 1)
        a += __shfl_down(a, off);
    if ((t & 63) == 0) wred[t >> 6] = a;
    __syncthreads();
    if (t == 0) {
        double s = 0.0;
#pragma unroll
        for (int i = 0; i < RBLOCK / 64; ++i) s += wred[i];
        out[0] = (float)s;
    }
}

extern "C" void kernel_launch(void* const* d_in, const int* in_sizes, int n_in,
                              void* d_out, int out_size, void* d_ws, size_t ws_size,
                              hipStream_t stream)
{
    const float* outputs = (const float*)d_in[0];
    const float* target  = (const float*)d_in[1];
    float* out = (float*)d_out;
    double* part = (double*)d_ws;   // GRID_TOTAL doubles = 20480 B

    yolo_loss_kernel<<<GRID_TOTAL, BLOCK, 0, stream>>>(outputs, target, part);
    reduce_kernel<<<1, RBLOCK, 0, stream>>>(part, out);
}